// Round 8
// baseline (2257.163 us; speedup 1.0000x reference)
//
#include <hip/hip_runtime.h>

#define T_SEQ 256
#define DMODEL 1024
#define NHEAD 16
#define HSZ 64
#define NLAYER 12
#define VOCAB 50257
#define NPAD 50304
#define FF 4096
#define MROWS 2048

using short8 = __attribute__((ext_vector_type(8))) short;
using f32x4  = __attribute__((ext_vector_type(4))) float;

__device__ __forceinline__ float bf2f(unsigned short u) {
    unsigned int x = ((unsigned int)u) << 16;
    return __builtin_bit_cast(float, x);
}
__device__ __forceinline__ unsigned short f2bf(float f) {
    unsigned int u = __builtin_bit_cast(unsigned int, f);
    unsigned int r = (u + 0x7fffu + ((u >> 16) & 1u)) >> 16;
    return (unsigned short)r;
}
__device__ __forceinline__ void async_copy16(const void* g, void* l) {
    __builtin_amdgcn_global_load_lds(
        (const __attribute__((address_space(1))) unsigned int*)g,
        (__attribute__((address_space(3))) unsigned int*)l, 16, 0, 0);
}

// ---------------------------------------------------------------------------
// Shared LN tail: given this thread's float4 of the row, reduce + write bf16
// ---------------------------------------------------------------------------
__device__ __forceinline__ void ln_tail(
    float4 v, const float* __restrict__ g, const float* __restrict__ b,
    int row, int tid, unsigned short* __restrict__ out)
{
    float s  = v.x + v.y + v.z + v.w;
    float ss = v.x * v.x + v.y * v.y + v.z * v.z + v.w * v.w;
    for (int o = 32; o > 0; o >>= 1) {
        s  += __shfl_down(s, o);
        ss += __shfl_down(ss, o);
    }
    __shared__ float ps[4], pss[4];
    int wave = tid >> 6, lane = tid & 63;
    if (lane == 0) { ps[wave] = s; pss[wave] = ss; }
    __syncthreads();
    float st  = ps[0] + ps[1] + ps[2] + ps[3];
    float sst = pss[0] + pss[1] + pss[2] + pss[3];
    float mu  = st * (1.0f / DMODEL);
    float var = sst * (1.0f / DMODEL) - mu * mu;
    float rstd = rsqrtf(var + 1e-5f);
    float4 gv = ((const float4*)g)[tid];
    float4 bv = ((const float4*)b)[tid];
    ushort4 o4;
    o4.x = f2bf((v.x - mu) * rstd * gv.x + bv.x);
    o4.y = f2bf((v.y - mu) * rstd * gv.y + bv.y);
    o4.z = f2bf((v.z - mu) * rstd * gv.z + bv.z);
    o4.w = f2bf((v.w - mu) * rstd * gv.w + bv.w);
    ((ushort4*)out)[(size_t)row * (DMODEL / 4) + tid] = o4;
}

// ---------------------------------------------------------------------------
// Embedding fused with layer-0 ln1
// ---------------------------------------------------------------------------
__global__ __launch_bounds__(256) void embed_ln_kernel(
    const int* __restrict__ idx, const float* __restrict__ tok,
    const float* __restrict__ pos, const float* __restrict__ g,
    const float* __restrict__ b, float* __restrict__ x,
    unsigned short* __restrict__ h)
{
    int row = blockIdx.x, tid = threadIdx.x;
    int t = row & (T_SEQ - 1);
    int token = idx[row];
    float4 a = ((const float4*)(tok + (size_t)token * DMODEL))[tid];
    float4 p = ((const float4*)(pos + (size_t)t * DMODEL))[tid];
    float4 v;
    v.x = a.x + p.x; v.y = a.y + p.y; v.z = a.z + p.z; v.w = a.w + p.w;
    ((float4*)(x + (size_t)row * DMODEL))[tid] = v;
    ln_tail(v, g, b, row, tid, h);
}

// ---------------------------------------------------------------------------
// Plain LayerNorm (used for ln2)
// ---------------------------------------------------------------------------
__global__ __launch_bounds__(256) void ln_kernel(
    const float* __restrict__ x, const float* __restrict__ g,
    const float* __restrict__ b, unsigned short* __restrict__ out)
{
    int row = blockIdx.x, tid = threadIdx.x;
    float4 v = ((const float4*)(x + (size_t)row * DMODEL))[tid];
    ln_tail(v, g, b, row, tid, out);
}

// ---------------------------------------------------------------------------
// fc2 partial merge + residual + NEXT layer's ln1 (or lnf), fused
// ---------------------------------------------------------------------------
__global__ __launch_bounds__(256) void fc2_merge_ln_kernel(
    const float* __restrict__ part, const float* __restrict__ bias,
    const float* __restrict__ g, const float* __restrict__ b,
    float* __restrict__ x, unsigned short* __restrict__ h)
{
    int row = blockIdx.x, tid = threadIdx.x;
    size_t o = (size_t)row * (DMODEL / 4) + tid;
    float4 p0 = ((const float4*)part)[o];
    float4 p1 = ((const float4*)part)[o + MROWS * (DMODEL / 4)];
    float4 bv = ((const float4*)bias)[tid];
    float4 v = ((float4*)x)[o];
    v.x += p0.x + p1.x + bv.x;
    v.y += p0.y + p1.y + bv.y;
    v.z += p0.z + p1.z + bv.z;
    v.w += p0.w + p1.w + bv.w;
    ((float4*)x)[o] = v;
    ln_tail(v, g, b, row, tid, h);
}

// ---------------------------------------------------------------------------
// Weight transpose: in [R,C] f32 -> out [C,R] bf16; cols [C, Cout) zero-filled
// ---------------------------------------------------------------------------
__global__ __launch_bounds__(256) void wtranspose_kernel(
    const float* __restrict__ in, unsigned short* __restrict__ out,
    int R, int C, int Cout, long in_l, long out_l)
{
    int lyr = blockIdx.z;
    in  += (size_t)lyr * in_l;
    out += (size_t)lyr * out_l;
    __shared__ float tile[32][33];
    int tx = threadIdx.x & 31, ty = threadIdx.x >> 5;
    int c0 = blockIdx.x * 32, r0 = blockIdx.y * 32;
    #pragma unroll
    for (int i = 0; i < 4; i++) {
        int r = r0 + ty + i * 8, c = c0 + tx;
        tile[ty + i * 8][tx] = (c < C) ? in[(size_t)r * C + c] : 0.f;
    }
    __syncthreads();
    #pragma unroll
    for (int i = 0; i < 4; i++) {
        int c = c0 + ty + i * 8, r = r0 + tx;
        if (c < Cout) out[(size_t)c * R + r] = f2bf(tile[tx][ty + i * 8]);
    }
}

// ---------------------------------------------------------------------------
// QKV weight pack: Wq/Wk/Wv [H,D,HS] f32 -> out[n, d] bf16, n=seg*1024+h*64+s
// ---------------------------------------------------------------------------
__global__ __launch_bounds__(256) void qkvpack_kernel(
    const float* __restrict__ Wq, const float* __restrict__ Wk,
    const float* __restrict__ Wv, unsigned short* __restrict__ out,
    long w_l, long out_l)
{
    int z = blockIdx.z;
    int lyr = z / 48, r48 = z % 48;
    int seg = r48 >> 4, hh = r48 & 15;
    const float* W = (seg == 0 ? Wq : seg == 1 ? Wk : Wv)
                     + (size_t)lyr * w_l + (size_t)hh * DMODEL * HSZ;
    unsigned short* o = out + (size_t)lyr * out_l
                      + (size_t)(seg * 1024 + hh * 64) * DMODEL;
    __shared__ float tile[32][33];
    int tx = threadIdx.x & 31, ty = threadIdx.x >> 5;
    int d0 = blockIdx.x * 32, s0 = blockIdx.y * 32;
    #pragma unroll
    for (int i = 0; i < 4; i++)
        tile[ty + i * 8][tx] = W[(size_t)(d0 + ty + i * 8) * HSZ + s0 + tx];
    __syncthreads();
    #pragma unroll
    for (int i = 0; i < 4; i++)
        o[(size_t)(s0 + ty + i * 8) * DMODEL + d0 + tx] = f2bf(tile[tx][ty + i * 8]);
}

// ---------------------------------------------------------------------------
// Shared bf16 MFMA GEMM core, 2-phase double-buffered:
//   stage(t+1) issued BEFORE compute(t); ONE barrier per K-step (compiler
//   emits vmcnt(0)+lgkmcnt(0) drain at the barrier -> tile t+1 landed and all
//   reads of buf[cur] finished before it is overwritten). Race-free: stage
//   always targets the buffer not being read this step.
// ---------------------------------------------------------------------------
template<int MF, bool QKV, bool RELU, bool RES, bool CBF16>
__device__ __forceinline__ void gemm_core(
    const unsigned short* __restrict__ A, int lda,
    const unsigned short* __restrict__ Bt, int ldb,
    const float* __restrict__ bias,
    void* __restrict__ Cv, int ldc,
    const float* __restrict__ res, int ldr,
    int N, int K,
    unsigned short* __restrict__ vtout)
{
    constexpr int BM = MF * 32;
    __shared__ __align__(16) char As[2][BM * 128];
    __shared__ __align__(16) char Bs[2][128 * 128];
    int tid = threadIdx.x;
    int wave = tid >> 6, lane = tid & 63;
    int wr = wave >> 1, wc = wave & 1;
    int m0 = blockIdx.x * BM, n0 = blockIdx.y * 128;

    f32x4 acc[MF][4];
    #pragma unroll
    for (int m = 0; m < MF; m++)
        #pragma unroll
        for (int n = 0; n < 4; n++)
            acc[m][n] = (f32x4){0.f, 0.f, 0.f, 0.f};

    int ksw = (((lane & 7) ^ (lane >> 3)) << 4);
    int KT = K >> 6;

    auto stage = [&](int kt, int bi) {
        int k0 = kt << 6;
        #pragma unroll
        for (int j = 0; j < MF; j++) {
            int row = (wave * MF + j) * 8 + (lane >> 3);
            const char* src = (const char*)A + ((size_t)(m0 + row) * lda + k0) * 2 + ksw;
            async_copy16(src, As[bi] + (wave * MF + j) * 1024);
        }
        #pragma unroll
        for (int j = 0; j < 4; j++) {
            int nrow = (wave * 4 + j) * 8 + (lane >> 3);
            const char* src = (const char*)Bt + ((size_t)(n0 + nrow) * ldb + k0) * 2 + ksw;
            async_copy16(src, Bs[bi] + (wave * 4 + j) * 1024);
        }
    };

    stage(0, 0);
    __syncthreads();                    // vmcnt(0) drain: tile 0 ready
    int cur = 0;
    for (int kt = 0; kt < KT; kt++) {
        if (kt + 1 < KT) stage(kt + 1, cur ^ 1);   // overlap with compute
        #pragma unroll
        for (int ks = 0; ks < 2; ks++) {
            int kb = ks * 64 + ((lane >> 4) << 4);
            short8 a[MF], b[4];
            #pragma unroll
            for (int m = 0; m < MF; m++) {
                int r = wr * (MF * 16) + m * 16 + (lane & 15);
                a[m] = *(const short8*)(const void*)(As[cur] + r * 128 + (kb ^ ((r & 7) << 4)));
            }
            #pragma unroll
            for (int n = 0; n < 4; n++) {
                int c = wc * 64 + n * 16 + (lane & 15);
                b[n] = *(const short8*)(const void*)(Bs[cur] + c * 128 + (kb ^ ((c & 7) << 4)));
            }
            #pragma unroll
            for (int m = 0; m < MF; m++)
                #pragma unroll
                for (int n = 0; n < 4; n++)
                    acc[m][n] = __builtin_amdgcn_mfma_f32_16x16x32_bf16(a[m], b[n], acc[m][n], 0, 0, 0);
        }
        __syncthreads();                // drain: tile kt+1 landed, reads done
        cur ^= 1;
    }
    #pragma unroll
    for (int m = 0; m < MF; m++) {
        int rowb = m0 + wr * (MF * 16) + m * 16 + ((lane >> 4) << 2);
        #pragma unroll
        for (int n = 0; n < 4; n++) {
            int col = n0 + wc * 64 + n * 16 + (lane & 15);
            if (col < N) {
                float bi = bias ? bias[col] : 0.f;
                #pragma unroll
                for (int r2 = 0; r2 < 4; r2++) {
                    float v = acc[m][n][r2] + bi;
                    if (RELU) v = fmaxf(v, 0.f);
                    int row = rowb + r2;
                    if (RES) v += res[(size_t)row * ldr + col];
                    if (QKV && col >= 2048) {
                        int hh = (col - 2048) >> 6, sdim = (col - 2048) & 63;
                        int bb = row >> 8, tt = row & 255;
                        vtout[((((size_t)bb * NHEAD + hh) * HSZ + sdim) * T_SEQ) + tt] = f2bf(v);
                    } else if (CBF16) {
                        ((unsigned short*)Cv)[(size_t)row * ldc + col] = f2bf(v);
                    } else {
                        ((float*)Cv)[(size_t)row * ldc + col] = v;
                    }
                }
            }
        }
    }
}

__global__ __launch_bounds__(256) void gemm_qkv(
    const unsigned short* __restrict__ A, const unsigned short* __restrict__ Bt,
    unsigned short* __restrict__ C, unsigned short* __restrict__ vtout)
{
    gemm_core<4, true, false, false, true>(
        A, DMODEL, Bt, DMODEL, nullptr, C, 3072, nullptr, 0, 3072, DMODEL, vtout);
}

__global__ __launch_bounds__(256) void gemm_fc1(
    const unsigned short* __restrict__ A, const unsigned short* __restrict__ Bt,
    const float* __restrict__ bias, unsigned short* __restrict__ C)
{
    gemm_core<4, false, true, false, true>(
        A, DMODEL, Bt, DMODEL, bias, C, FF, nullptr, 0, FF, DMODEL, nullptr);
}

// fc2 split-K: blockIdx.z selects K-half (2048 each); writes f32 partials.
__global__ __launch_bounds__(256) void gemm_fc2(
    const unsigned short* __restrict__ A, const unsigned short* __restrict__ Bt,
    float* __restrict__ part)
{
    int z = blockIdx.z;
    gemm_core<2, false, false, false, false>(
        A + z * 2048, FF, Bt + z * 2048, FF, nullptr,
        part + (size_t)z * MROWS * DMODEL, DMODEL, nullptr, 0,
        DMODEL, 2048, nullptr);
}

__global__ __launch_bounds__(256) void gemm_lm(
    const unsigned short* __restrict__ A, const unsigned short* __restrict__ Bt,
    const float* __restrict__ bias, float* __restrict__ C)
{
    gemm_core<4, false, false, false, false>(
        A, DMODEL, Bt, DMODEL, bias, C, VOCAB, nullptr, 0, VOCAB, DMODEL, nullptr);
}

// ---------------------------------------------------------------------------
// Fused flash attention (MFMA). Grid (4 qtiles, 16 h, 8 b), 4 waves.
// ---------------------------------------------------------------------------
__global__ __launch_bounds__(256) void attn_fused_kernel(
    const unsigned short* __restrict__ qkv, const unsigned short* __restrict__ vt,
    float* __restrict__ x)
{
    int qt = blockIdx.x, hh = blockIdx.y, b = blockIdx.z;
    int tid = threadIdx.x;
    int wave = tid >> 6, lane = tid & 63;
    int g = lane >> 4, q = lane & 15;

    __shared__ __align__(16) char Kb[2][8192];
    __shared__ __align__(16) char Vb[2][8192];
    __shared__ __align__(16) char Plds[4][2048];

    int qrow = b * T_SEQ + qt * 64 + wave * 16 + q;
    const char* qp = (const char*)qkv + ((size_t)qrow * 3072 + hh * HSZ) * 2;
    short8 qreg[2];
    qreg[0] = *(const short8*)(const void*)(qp + (g << 4));
    qreg[1] = *(const short8*)(const void*)(qp + 64 + (g << 4));

    char* Pw = Plds[wave];

    f32x4 oacc[4];
    #pragma unroll
    for (int f = 0; f < 4; f++) oacc[f] = (f32x4){0.f, 0.f, 0.f, 0.f};
    float m_run = -1e30f, l_run = 0.f;

    int srow = wave * 8 + (lane >> 3);
    int sbyte = ((lane & 7) << 4) ^ ((srow & 7) << 4);

    auto stage = [&](int kt, int bi) {
        #pragma unroll
        for (int c = 0; c < 2; c++) {
            int row = c * 32 + srow;
            const char* src = (const char*)qkv +
                ((size_t)(b * T_SEQ + kt * 64 + row) * 3072 + 1024 + hh * HSZ) * 2 + sbyte;
            async_copy16(src, Kb[bi] + c * 4096 + wave * 1024);
        }
        #pragma unroll
        for (int c = 0; c < 2; c++) {
            int row = c * 32 + srow;
            const char* src = (const char*)vt +
                (((size_t)(b * NHEAD + hh) * HSZ + row) * T_SEQ + kt * 64) * 2 + sbyte;
            async_copy16(src, Vb[bi] + c * 4096 + wave * 1024);
        }
    };

    stage(0, 0);
    for (int kt = 0; kt <= qt; kt++) {
        int bi = kt & 1;
        __syncthreads();
        if (kt < qt) stage(kt + 1, bi ^ 1);

        f32x4 sacc[4];
        #pragma unroll
        for (int f = 0; f < 4; f++) sacc[f] = (f32x4){0.f, 0.f, 0.f, 0.f};
        #pragma unroll
        for (int ks = 0; ks < 2; ks++) {
            int kb = ks * 64 + (g << 4);
            #pragma unroll
            for (int f = 0; f < 4; f++) {
                int u = f * 16 + q;
                short8 kf = *(const short8*)(const void*)(Kb[bi] + u * 128 + (kb ^ ((u & 7) << 4)));
                sacc[f] = __builtin_amdgcn_mfma_f32_16x16x32_bf16(kf, qreg[ks], sacc[f], 0, 0, 0);
            }
        }
        float sv[4][4];
        #pragma unroll
        for (int f = 0; f < 4; f++)
            #pragma unroll
            for (int r = 0; r < 4; r++) {
                float v = sacc[f][r] * 0.125f;
                if (kt == qt) {
                    int u_loc = f * 16 + g * 4 + r;
                    if (u_loc > wave * 16 + q) v = -1e30f;
                }
                sv[f][r] = v;
            }
        float pm = -1e30f;
        #pragma unroll
        for (int f = 0; f < 4; f++)
            #pragma unroll
            for (int r = 0; r < 4; r++) pm = fmaxf(pm, sv[f][r]);
        pm = fmaxf(pm, __shfl_xor(pm, 16));
        pm = fmaxf(pm, __shfl_xor(pm, 32));
        float mnew = fmaxf(m_run, pm);
        float corr = __expf(m_run - mnew);
        float p[4][4];
        float ls = 0.f;
        #pragma unroll
        for (int f = 0; f < 4; f++)
            #pragma unroll
            for (int r = 0; r < 4; r++) {
                p[f][r] = __expf(sv[f][r] - mnew);
                ls += p[f][r];
            }
        ls += __shfl_xor(ls, 16);
        ls += __shfl_xor(ls, 32);
        l_run = l_run * corr + ls;
        m_run = mnew;
        #pragma unroll
        for (int r = 0; r < 4; r++) {
            float cr = __shfl(corr, (lane & 48) | (g * 4 + r));
            #pragma unroll
            for (int f = 0; f < 4; f++) oacc[f][r] *= cr;
        }
        #pragma unroll
        for (int f = 0; f < 4; f++)
            #pragma unroll
            for (int rp = 0; rp < 2; rp++) {
                int ue = f * 16 + g * 4 + rp * 2;
                unsigned int pk = (unsigned int)f2bf(p[f][rp * 2])
                                | ((unsigned int)f2bf(p[f][rp * 2 + 1]) << 16);
                *(unsigned int*)(void*)(Pw + q * 128 + ((ue * 2) ^ ((q & 7) << 4))) = pk;
            }
        #pragma unroll
        for (int ks = 0; ks < 2; ks++) {
            int kb = ks * 64 + (g << 4);
            short8 pa = *(const short8*)(const void*)(Pw + q * 128 + (kb ^ ((q & 7) << 4)));
            #pragma unroll
            for (int f = 0; f < 4; f++) {
                int s = f * 16 + q;
                short8 vf = *(const short8*)(const void*)(Vb[bi] + s * 128 + (kb ^ ((s & 7) << 4)));
                oacc[f] = __builtin_amdgcn_mfma_f32_16x16x32_bf16(pa, vf, oacc[f], 0, 0, 0);
            }
        }
    }
    float inv = 1.0f / l_run;
    #pragma unroll
    for (int r = 0; r < 4; r++) {
        float ir = __shfl(inv, (lane & 48) | (g * 4 + r));
        int row_g = b * T_SEQ + qt * 64 + wave * 16 + g * 4 + r;
        #pragma unroll
        for (int f = 0; f < 4; f++) {
            size_t xi = (size_t)row_g * DMODEL + hh * HSZ + f * 16 + q;
            x[xi] += oacc[f][r] * ir;
        }
    }
}

// ---------------------------------------------------------------------------
// Loss pass 1: per-row online logsumexp over logits (float4) -> nll[row]
// ---------------------------------------------------------------------------
__global__ __launch_bounds__(256) void loss1_kernel(
    const float* __restrict__ logits, const int* __restrict__ targets,
    float* __restrict__ nll)
{
    int r = blockIdx.x, tid = threadIdx.x;
    const float* row = logits + (size_t)r * VOCAB;
    const float4* row4 = (const float4*)row;
    float m = -3.4e38f, s = 0.f;
    for (int v = tid; v < VOCAB / 4; v += 256) {
        float4 x4 = row4[v];
        float lm = fmaxf(fmaxf(x4.x, x4.y), fmaxf(x4.z, x4.w));
        float nm = fmaxf(m, lm);
        s = s * __expf(m - nm) + __expf(x4.x - nm) + __expf(x4.y - nm)
          + __expf(x4.z - nm) + __expf(x4.w - nm);
        m = nm;
    }
    if (tid == 0) {
        float xv = row[VOCAB - 1];
        float nm = fmaxf(m, xv);
        s = s * __expf(m - nm) + __expf(xv - nm);
        m = nm;
    }
    __shared__ float ms[256], ssh[256];
    ms[tid] = m; ssh[tid] = s;
    __syncthreads();
    for (int o = 128; o > 0; o >>= 1) {
        if (tid < o) {
            float m1 = ms[tid], s1 = ssh[tid];
            float m2 = ms[tid + o], s2 = ssh[tid + o];
            float nm = fmaxf(m1, m2);
            ssh[tid] = s1 * __expf(m1 - nm) + s2 * __expf(m2 - nm);
            ms[tid] = nm;
        }
        __syncthreads();
    }
    if (tid == 0) nll[r] = logf(ssh[0]) + ms[0] - row[targets[r]];
}

__global__ __launch_bounds__(256) void loss2_kernel(
    const float* __restrict__ nll, float* __restrict__ out)
{
    int tid = threadIdx.x;
    float s = 0.f;
    for (int i = tid; i < MROWS; i += 256) s += nll[i];
    __shared__ float red[256];
    red[tid] = s;
    __syncthreads();
    for (int o = 128; o > 0; o >>= 1) {
        if (tid < o) red[tid] += red[tid + o];
        __syncthreads();
    }
    if (tid == 0) out[0] = red[0] * (1.0f / MROWS);
}

// ---------------------------------------------------------------------------
extern "C" void kernel_launch(void* const* d_in, const int* in_sizes, int n_in,
                              void* d_out, int out_size, void* d_ws, size_t ws_size,
                              hipStream_t stream)
{
    const int*   idx  = (const int*)d_in[0];
    const int*   tgt  = (const int*)d_in[1];
    const float* tok  = (const float*)d_in[2];
    const float* pos  = (const float*)d_in[3];
    const float* Wq   = (const float*)d_in[4];
    const float* Wk   = (const float*)d_in[5];
    const float* Wv   = (const float*)d_in[6];
    const float* ln1g = (const float*)d_in[7];
    const float* ln1b = (const float*)d_in[8];
    const float* ln2g = (const float*)d_in[9];
    const float* ln2b = (const float*)d_in[10];
    const float* fc1w = (const float*)d_in[11];
    const float* fc1b = (const float*)d_in[12];
    const float* fc2w = (const float*)d_in[13];
    const float* fc2b = (const float*)d_in[14];
    const float* lnfg = (const float*)d_in[15];
    const float* lnfb = (const float*)d_in[16];
    const float* lmw  = (const float*)d_in[17];
    const float* lmb  = (const float*)d_in[18];

    char* ws = (char*)d_ws;
    float*          x    = (float*)(ws + 0);                  // 8.39 MB
    unsigned short* h    = (unsigned short*)(ws + 8388608);   // 4.19 MB
    unsigned short* qkv  = (unsigned short*)(ws + 12582912);  // 12.58 MB
    unsigned short* vt   = (unsigned short*)(ws + 25165824);  // 4.19 MB
    unsigned short* mid  = (unsigned short*)(ws + 29360128);  // 16.78 MB
    float*          nll  = (float*)(ws + 46137344);           // 8 KB
    float*          fc2p = (float*)(ws + 46145536);           // 16.78 MB [2][2048][1024]
    unsigned short* lmwt = (unsigned short*)(ws + 62922752);  // 103.02 MB [50304][1024]
    // end lmwt: 165945344
    const size_t UP_NEED = 442769408ull;
    bool upfront = (ws_size >= UP_NEED);
    unsigned short* qkvt = (unsigned short*)(ws + 165945344);
    unsigned short* fc1t, * fc2t;
    long qkvt_l, fc1t_l, fc2t_l;
    if (upfront) {
        fc1t = (unsigned short*)(ws + 241442816);
        fc2t = (unsigned short*)(ws + 342106112);
        qkvt_l = 3072 * 1024; fc1t_l = (long)FF * 1024; fc2t_l = (long)1024 * FF;
    } else {
        fc1t = (unsigned short*)(ws + 172236800);
        fc2t = (unsigned short*)(ws + 180625408);
        qkvt_l = 0; fc1t_l = 0; fc2t_l = 0;
    }
    float* logits = (float*)d_out;
    float* lossp  = logits + (size_t)MROWS * VOCAB;

    const long WQKV_L = (long)NHEAD * DMODEL * HSZ;
    if (upfront) {
        qkvpack_kernel<<<dim3(32, 2, 48 * NLAYER), 256, 0, stream>>>(
            Wq, Wk, Wv, qkvt, WQKV_L, qkvt_l);
        wtranspose_kernel<<<dim3(128, 32, NLAYER), 256, 0, stream>>>(
            fc1w, fc1t, DMODEL, FF, FF, (long)DMODEL * FF, fc1t_l);
        wtranspose_kernel<<<dim3(32, 128, NLAYER), 256, 0, stream>>>(
            fc2w, fc2t, FF, DMODEL, DMODEL, (long)FF * DMODEL, fc2t_l);
    }
    wtranspose_kernel<<<dim3(1572, 32, 1), 256, 0, stream>>>(
        lmw, lmwt, DMODEL, VOCAB, NPAD, 0, 0);

    // embed + layer-0 ln1 fused
    embed_ln_kernel<<<MROWS, 256, 0, stream>>>(idx, tok, pos, ln1g, ln1b, x, h);

    for (int l = 0; l < NLAYER; l++) {
        unsigned short* qkvt_p = qkvt + (size_t)l * qkvt_l;
        unsigned short* fc1t_p = fc1t + (size_t)l * fc1t_l;
        unsigned short* fc2t_p = fc2t + (size_t)l * fc2t_l;
        if (!upfront) {
            qkvpack_kernel<<<dim3(32, 2, 48), 256, 0, stream>>>(
                Wq + (size_t)l * WQKV_L, Wk + (size_t)l * WQKV_L,
                Wv + (size_t)l * WQKV_L, qkvt, WQKV_L, 0);
            wtranspose_kernel<<<dim3(128, 32, 1), 256, 0, stream>>>(
                fc1w + (size_t)l * DMODEL * FF, fc1t, DMODEL, FF, FF, 0, 0);
            wtranspose_kernel<<<dim3(32, 128, 1), 256, 0, stream>>>(
                fc2w + (size_t)l * FF * DMODEL, fc2t, FF, DMODEL, DMODEL, 0, 0);
        }
        gemm_qkv<<<dim3(16, 24), 256, 0, stream>>>(h, qkvt_p, qkv, vt);
        attn_fused_kernel<<<dim3(4, NHEAD, 8), 256, 0, stream>>>(qkv, vt, x);
        ln_kernel<<<MROWS, 256, 0, stream>>>(x, ln2g + l * DMODEL, ln2b + l * DMODEL, h);
        gemm_fc1<<<dim3(16, 32), 256, 0, stream>>>(h, fc1t_p, fc1b + (size_t)l * FF, mid);
        gemm_fc2<<<dim3(32, 8, 2), 256, 0, stream>>>(mid, fc2t_p, fc2p);
        // merge + residual + next ln1 (or lnf on last layer), fused
        const float* ng = (l < NLAYER - 1) ? ln1g + (l + 1) * DMODEL : lnfg;
        const float* nb = (l < NLAYER - 1) ? ln1b + (l + 1) * DMODEL : lnfb;
        fc2_merge_ln_kernel<<<MROWS, 256, 0, stream>>>(
            fc2p, fc2b + (size_t)l * DMODEL, ng, nb, x, h);
    }

    gemm_lm<<<dim3(16, 393), 256, 0, stream>>>(h, lmwt, lmb, logits);

    loss1_kernel<<<MROWS, 256, 0, stream>>>(logits, tgt, nll);
    loss2_kernel<<<1, 256, 0, stream>>>(nll, lossp);
}

// Round 9
// 2122.421 us; speedup vs baseline: 1.0635x; 1.0635x over previous
//
#include <hip/hip_runtime.h>

#define T_SEQ 256
#define DMODEL 1024
#define NHEAD 16
#define HSZ 64
#define NLAYER 12
#define VOCAB 50257
#define NPAD 50304
#define FF 4096
#define MROWS 2048

using short8 = __attribute__((ext_vector_type(8))) short;
using f32x4  = __attribute__((ext_vector_type(4))) float;

__device__ __forceinline__ float bf2f(unsigned short u) {
    unsigned int x = ((unsigned int)u) << 16;
    return __builtin_bit_cast(float, x);
}
__device__ __forceinline__ unsigned short f2bf(float f) {
    unsigned int u = __builtin_bit_cast(unsigned int, f);
    unsigned int r = (u + 0x7fffu + ((u >> 16) & 1u)) >> 16;
    return (unsigned short)r;
}
__device__ __forceinline__ void async_copy16(const void* g, void* l) {
    __builtin_amdgcn_global_load_lds(
        (const __attribute__((address_space(1))) unsigned int*)g,
        (__attribute__((address_space(3))) unsigned int*)l, 16, 0, 0);
}

// ---------------------------------------------------------------------------
// Shared LN tail: given this thread's float4 of the row, reduce + write bf16
// ---------------------------------------------------------------------------
__device__ __forceinline__ void ln_tail(
    float4 v, const float* __restrict__ g, const float* __restrict__ b,
    int row, int tid, unsigned short* __restrict__ out)
{
    float s  = v.x + v.y + v.z + v.w;
    float ss = v.x * v.x + v.y * v.y + v.z * v.z + v.w * v.w;
    for (int o = 32; o > 0; o >>= 1) {
        s  += __shfl_down(s, o);
        ss += __shfl_down(ss, o);
    }
    __shared__ float ps[4], pss[4];
    int wave = tid >> 6, lane = tid & 63;
    if (lane == 0) { ps[wave] = s; pss[wave] = ss; }
    __syncthreads();
    float st  = ps[0] + ps[1] + ps[2] + ps[3];
    float sst = pss[0] + pss[1] + pss[2] + pss[3];
    float mu  = st * (1.0f / DMODEL);
    float var = sst * (1.0f / DMODEL) - mu * mu;
    float rstd = rsqrtf(var + 1e-5f);
    float4 gv = ((const float4*)g)[tid];
    float4 bv = ((const float4*)b)[tid];
    ushort4 o4;
    o4.x = f2bf((v.x - mu) * rstd * gv.x + bv.x);
    o4.y = f2bf((v.y - mu) * rstd * gv.y + bv.y);
    o4.z = f2bf((v.z - mu) * rstd * gv.z + bv.z);
    o4.w = f2bf((v.w - mu) * rstd * gv.w + bv.w);
    ((ushort4*)out)[(size_t)row * (DMODEL / 4) + tid] = o4;
}

// ---------------------------------------------------------------------------
// Embedding fused with layer-0 ln1
// ---------------------------------------------------------------------------
__global__ __launch_bounds__(256) void embed_ln_kernel(
    const int* __restrict__ idx, const float* __restrict__ tok,
    const float* __restrict__ pos, const float* __restrict__ g,
    const float* __restrict__ b, float* __restrict__ x,
    unsigned short* __restrict__ h)
{
    int row = blockIdx.x, tid = threadIdx.x;
    int t = row & (T_SEQ - 1);
    int token = idx[row];
    float4 a = ((const float4*)(tok + (size_t)token * DMODEL))[tid];
    float4 p = ((const float4*)(pos + (size_t)t * DMODEL))[tid];
    float4 v;
    v.x = a.x + p.x; v.y = a.y + p.y; v.z = a.z + p.z; v.w = a.w + p.w;
    ((float4*)(x + (size_t)row * DMODEL))[tid] = v;
    ln_tail(v, g, b, row, tid, h);
}

// ---------------------------------------------------------------------------
// Plain LayerNorm (used for ln2)
// ---------------------------------------------------------------------------
__global__ __launch_bounds__(256) void ln_kernel(
    const float* __restrict__ x, const float* __restrict__ g,
    const float* __restrict__ b, unsigned short* __restrict__ out)
{
    int row = blockIdx.x, tid = threadIdx.x;
    float4 v = ((const float4*)(x + (size_t)row * DMODEL))[tid];
    ln_tail(v, g, b, row, tid, out);
}

// ---------------------------------------------------------------------------
// fc2 partial merge + residual + NEXT layer's ln1 (or lnf), fused
// ---------------------------------------------------------------------------
__global__ __launch_bounds__(256) void fc2_merge_ln_kernel(
    const float* __restrict__ part, const float* __restrict__ bias,
    const float* __restrict__ g, const float* __restrict__ b,
    float* __restrict__ x, unsigned short* __restrict__ h)
{
    int row = blockIdx.x, tid = threadIdx.x;
    size_t o = (size_t)row * (DMODEL / 4) + tid;
    float4 p0 = ((const float4*)part)[o];
    float4 p1 = ((const float4*)part)[o + MROWS * (DMODEL / 4)];
    float4 bv = ((const float4*)bias)[tid];
    float4 v = ((float4*)x)[o];
    v.x += p0.x + p1.x + bv.x;
    v.y += p0.y + p1.y + bv.y;
    v.z += p0.z + p1.z + bv.z;
    v.w += p0.w + p1.w + bv.w;
    ((float4*)x)[o] = v;
    ln_tail(v, g, b, row, tid, h);
}

// ---------------------------------------------------------------------------
// Weight transpose: in [R,C] f32 -> out [C,R] bf16; cols [C, Cout) zero-filled
// ---------------------------------------------------------------------------
__global__ __launch_bounds__(256) void wtranspose_kernel(
    const float* __restrict__ in, unsigned short* __restrict__ out,
    int R, int C, int Cout, long in_l, long out_l)
{
    int lyr = blockIdx.z;
    in  += (size_t)lyr * in_l;
    out += (size_t)lyr * out_l;
    __shared__ float tile[32][33];
    int tx = threadIdx.x & 31, ty = threadIdx.x >> 5;
    int c0 = blockIdx.x * 32, r0 = blockIdx.y * 32;
    #pragma unroll
    for (int i = 0; i < 4; i++) {
        int r = r0 + ty + i * 8, c = c0 + tx;
        tile[ty + i * 8][tx] = (c < C) ? in[(size_t)r * C + c] : 0.f;
    }
    __syncthreads();
    #pragma unroll
    for (int i = 0; i < 4; i++) {
        int c = c0 + ty + i * 8, r = r0 + tx;
        if (c < Cout) out[(size_t)c * R + r] = f2bf(tile[tx][ty + i * 8]);
    }
}

// ---------------------------------------------------------------------------
// QKV weight pack: Wq/Wk/Wv [H,D,HS] f32 -> out[n, d] bf16, n=seg*1024+h*64+s
// ---------------------------------------------------------------------------
__global__ __launch_bounds__(256) void qkvpack_kernel(
    const float* __restrict__ Wq, const float* __restrict__ Wk,
    const float* __restrict__ Wv, unsigned short* __restrict__ out,
    long w_l, long out_l)
{
    int z = blockIdx.z;
    int lyr = z / 48, r48 = z % 48;
    int seg = r48 >> 4, hh = r48 & 15;
    const float* W = (seg == 0 ? Wq : seg == 1 ? Wk : Wv)
                     + (size_t)lyr * w_l + (size_t)hh * DMODEL * HSZ;
    unsigned short* o = out + (size_t)lyr * out_l
                      + (size_t)(seg * 1024 + hh * 64) * DMODEL;
    __shared__ float tile[32][33];
    int tx = threadIdx.x & 31, ty = threadIdx.x >> 5;
    int d0 = blockIdx.x * 32, s0 = blockIdx.y * 32;
    #pragma unroll
    for (int i = 0; i < 4; i++)
        tile[ty + i * 8][tx] = W[(size_t)(d0 + ty + i * 8) * HSZ + s0 + tx];
    __syncthreads();
    #pragma unroll
    for (int i = 0; i < 4; i++)
        o[(size_t)(s0 + ty + i * 8) * DMODEL + d0 + tx] = f2bf(tile[tx][ty + i * 8]);
}

// ---------------------------------------------------------------------------
// Shared bf16 MFMA GEMM core (single-buffer 2-barrier; dbuf measured neutral
// R8). Templated wave count: BM = (WAVES/2)*MF*16, per-wave tile = MF*16 x 64.
// WAVES=8 variant amortizes staging over a 256-row tile at same VGPR class.
// ---------------------------------------------------------------------------
template<int MF, int WAVES, bool QKV, bool RELU, bool RES, bool CBF16>
__device__ __forceinline__ void gemm_core(
    const unsigned short* __restrict__ A, int lda,
    const unsigned short* __restrict__ Bt, int ldb,
    const float* __restrict__ bias,
    void* __restrict__ Cv, int ldc,
    const float* __restrict__ res, int ldr,
    int N, int K,
    unsigned short* __restrict__ vtout)
{
    constexpr int BM = (WAVES / 2) * MF * 16;
    constexpr int BJ = 16 / WAVES;          // B staging iterations per wave
    __shared__ __align__(16) char As[BM * 128];
    __shared__ __align__(16) char Bs[128 * 128];
    int tid = threadIdx.x;
    int wave = tid >> 6, lane = tid & 63;
    int wr = wave >> 1, wc = wave & 1;
    int m0 = blockIdx.x * BM, n0 = blockIdx.y * 128;

    f32x4 acc[MF][4];
    #pragma unroll
    for (int m = 0; m < MF; m++)
        #pragma unroll
        for (int n = 0; n < 4; n++)
            acc[m][n] = (f32x4){0.f, 0.f, 0.f, 0.f};

    int ksw = (((lane & 7) ^ (lane >> 3)) << 4);
    int KT = K >> 6;
    for (int kt = 0; kt < KT; kt++) {
        int k0 = kt << 6;
        __syncthreads();
        #pragma unroll
        for (int j = 0; j < MF; j++) {
            int row = (wave * MF + j) * 8 + (lane >> 3);
            const char* src = (const char*)A + ((size_t)(m0 + row) * lda + k0) * 2 + ksw;
            async_copy16(src, As + (wave * MF + j) * 1024);
        }
        #pragma unroll
        for (int j = 0; j < BJ; j++) {
            int nrow = (wave * BJ + j) * 8 + (lane >> 3);
            const char* src = (const char*)Bt + ((size_t)(n0 + nrow) * ldb + k0) * 2 + ksw;
            async_copy16(src, Bs + (wave * BJ + j) * 1024);
        }
        __syncthreads();
        #pragma unroll
        for (int ks = 0; ks < 2; ks++) {
            int kb = ks * 64 + ((lane >> 4) << 4);
            short8 a[MF], b[4];
            #pragma unroll
            for (int m = 0; m < MF; m++) {
                int r = wr * (MF * 16) + m * 16 + (lane & 15);
                a[m] = *(const short8*)(const void*)(As + r * 128 + (kb ^ ((r & 7) << 4)));
            }
            #pragma unroll
            for (int n = 0; n < 4; n++) {
                int c = wc * 64 + n * 16 + (lane & 15);
                b[n] = *(const short8*)(const void*)(Bs + c * 128 + (kb ^ ((c & 7) << 4)));
            }
            #pragma unroll
            for (int m = 0; m < MF; m++)
                #pragma unroll
                for (int n = 0; n < 4; n++)
                    acc[m][n] = __builtin_amdgcn_mfma_f32_16x16x32_bf16(a[m], b[n], acc[m][n], 0, 0, 0);
        }
    }
    #pragma unroll
    for (int m = 0; m < MF; m++) {
        int rowb = m0 + wr * (MF * 16) + m * 16 + ((lane >> 4) << 2);
        #pragma unroll
        for (int n = 0; n < 4; n++) {
            int col = n0 + wc * 64 + n * 16 + (lane & 15);
            if (col < N) {
                float bi = bias ? bias[col] : 0.f;
                #pragma unroll
                for (int r2 = 0; r2 < 4; r2++) {
                    float v = acc[m][n][r2] + bi;
                    if (RELU) v = fmaxf(v, 0.f);
                    int row = rowb + r2;
                    if (RES) v += res[(size_t)row * ldr + col];
                    if (QKV && col >= 2048) {
                        int hh = (col - 2048) >> 6, sdim = (col - 2048) & 63;
                        int bb = row >> 8, tt = row & 255;
                        vtout[((((size_t)bb * NHEAD + hh) * HSZ + sdim) * T_SEQ) + tt] = f2bf(v);
                    } else if (CBF16) {
                        ((unsigned short*)Cv)[(size_t)row * ldc + col] = f2bf(v);
                    } else {
                        ((float*)Cv)[(size_t)row * ldc + col] = v;
                    }
                }
            }
        }
    }
}

__global__ __launch_bounds__(256) void gemm_qkv(
    const unsigned short* __restrict__ A, const unsigned short* __restrict__ Bt,
    unsigned short* __restrict__ C, unsigned short* __restrict__ vtout)
{
    gemm_core<4, 4, true, false, false, true>(
        A, DMODEL, Bt, DMODEL, nullptr, C, 3072, nullptr, 0, 3072, DMODEL, vtout);
}

__global__ __launch_bounds__(256) void gemm_fc1(
    const unsigned short* __restrict__ A, const unsigned short* __restrict__ Bt,
    const float* __restrict__ bias, unsigned short* __restrict__ C)
{
    gemm_core<4, 4, false, true, false, true>(
        A, DMODEL, Bt, DMODEL, bias, C, FF, nullptr, 0, FF, DMODEL, nullptr);
}

// fc2 split-K: blockIdx.z selects K-half (2048 each); writes f32 partials.
__global__ __launch_bounds__(256) void gemm_fc2(
    const unsigned short* __restrict__ A, const unsigned short* __restrict__ Bt,
    float* __restrict__ part)
{
    int z = blockIdx.z;
    gemm_core<2, 4, false, false, false, false>(
        A + z * 2048, FF, Bt + z * 2048, FF, nullptr,
        part + (size_t)z * MROWS * DMODEL, DMODEL, nullptr, 0,
        DMODEL, 2048, nullptr);
}

// LM head: 8 waves, 256x128 tile — 6 staging loads/thread/K-step (vs 8),
// half the B-panel refetches, same per-wave geometry (acc 64 VGPR).
__global__ __launch_bounds__(512) void gemm_lm(
    const unsigned short* __restrict__ A, const unsigned short* __restrict__ Bt,
    const float* __restrict__ bias, float* __restrict__ C)
{
    gemm_core<4, 8, false, false, false, false>(
        A, DMODEL, Bt, DMODEL, bias, C, VOCAB, nullptr, 0, VOCAB, DMODEL, nullptr);
}

// ---------------------------------------------------------------------------
// Fused flash attention (MFMA). Grid (4 qtiles, 16 h, 8 b), 4 waves.
// ---------------------------------------------------------------------------
__global__ __launch_bounds__(256) void attn_fused_kernel(
    const unsigned short* __restrict__ qkv, const unsigned short* __restrict__ vt,
    float* __restrict__ x)
{
    int qt = blockIdx.x, hh = blockIdx.y, b = blockIdx.z;
    int tid = threadIdx.x;
    int wave = tid >> 6, lane = tid & 63;
    int g = lane >> 4, q = lane & 15;

    __shared__ __align__(16) char Kb[2][8192];
    __shared__ __align__(16) char Vb[2][8192];
    __shared__ __align__(16) char Plds[4][2048];

    int qrow = b * T_SEQ + qt * 64 + wave * 16 + q;
    const char* qp = (const char*)qkv + ((size_t)qrow * 3072 + hh * HSZ) * 2;
    short8 qreg[2];
    qreg[0] = *(const short8*)(const void*)(qp + (g << 4));
    qreg[1] = *(const short8*)(const void*)(qp + 64 + (g << 4));

    char* Pw = Plds[wave];

    f32x4 oacc[4];
    #pragma unroll
    for (int f = 0; f < 4; f++) oacc[f] = (f32x4){0.f, 0.f, 0.f, 0.f};
    float m_run = -1e30f, l_run = 0.f;

    int srow = wave * 8 + (lane >> 3);
    int sbyte = ((lane & 7) << 4) ^ ((srow & 7) << 4);

    auto stage = [&](int kt, int bi) {
        #pragma unroll
        for (int c = 0; c < 2; c++) {
            int row = c * 32 + srow;
            const char* src = (const char*)qkv +
                ((size_t)(b * T_SEQ + kt * 64 + row) * 3072 + 1024 + hh * HSZ) * 2 + sbyte;
            async_copy16(src, Kb[bi] + c * 4096 + wave * 1024);
        }
        #pragma unroll
        for (int c = 0; c < 2; c++) {
            int row = c * 32 + srow;
            const char* src = (const char*)vt +
                (((size_t)(b * NHEAD + hh) * HSZ + row) * T_SEQ + kt * 64) * 2 + sbyte;
            async_copy16(src, Vb[bi] + c * 4096 + wave * 1024);
        }
    };

    stage(0, 0);
    for (int kt = 0; kt <= qt; kt++) {
        int bi = kt & 1;
        __syncthreads();
        if (kt < qt) stage(kt + 1, bi ^ 1);

        f32x4 sacc[4];
        #pragma unroll
        for (int f = 0; f < 4; f++) sacc[f] = (f32x4){0.f, 0.f, 0.f, 0.f};
        #pragma unroll
        for (int ks = 0; ks < 2; ks++) {
            int kb = ks * 64 + (g << 4);
            #pragma unroll
            for (int f = 0; f < 4; f++) {
                int u = f * 16 + q;
                short8 kf = *(const short8*)(const void*)(Kb[bi] + u * 128 + (kb ^ ((u & 7) << 4)));
                sacc[f] = __builtin_amdgcn_mfma_f32_16x16x32_bf16(kf, qreg[ks], sacc[f], 0, 0, 0);
            }
        }
        float sv[4][4];
        #pragma unroll
        for (int f = 0; f < 4; f++)
            #pragma unroll
            for (int r = 0; r < 4; r++) {
                float v = sacc[f][r] * 0.125f;
                if (kt == qt) {
                    int u_loc = f * 16 + g * 4 + r;
                    if (u_loc > wave * 16 + q) v = -1e30f;
                }
                sv[f][r] = v;
            }
        float pm = -1e30f;
        #pragma unroll
        for (int f = 0; f < 4; f++)
            #pragma unroll
            for (int r = 0; r < 4; r++) pm = fmaxf(pm, sv[f][r]);
        pm = fmaxf(pm, __shfl_xor(pm, 16));
        pm = fmaxf(pm, __shfl_xor(pm, 32));
        float mnew = fmaxf(m_run, pm);
        float corr = __expf(m_run - mnew);
        float p[4][4];
        float ls = 0.f;
        #pragma unroll
        for (int f = 0; f < 4; f++)
            #pragma unroll
            for (int r = 0; r < 4; r++) {
                p[f][r] = __expf(sv[f][r] - mnew);
                ls += p[f][r];
            }
        ls += __shfl_xor(ls, 16);
        ls += __shfl_xor(ls, 32);
        l_run = l_run * corr + ls;
        m_run = mnew;
        #pragma unroll
        for (int r = 0; r < 4; r++) {
            float cr = __shfl(corr, (lane & 48) | (g * 4 + r));
            #pragma unroll
            for (int f = 0; f < 4; f++) oacc[f][r] *= cr;
        }
        #pragma unroll
        for (int f = 0; f < 4; f++)
            #pragma unroll
            for (int rp = 0; rp < 2; rp++) {
                int ue = f * 16 + g * 4 + rp * 2;
                unsigned int pk = (unsigned int)f2bf(p[f][rp * 2])
                                | ((unsigned int)f2bf(p[f][rp * 2 + 1]) << 16);
                *(unsigned int*)(void*)(Pw + q * 128 + ((ue * 2) ^ ((q & 7) << 4))) = pk;
            }
        #pragma unroll
        for (int ks = 0; ks < 2; ks++) {
            int kb = ks * 64 + (g << 4);
            short8 pa = *(const short8*)(const void*)(Pw + q * 128 + (kb ^ ((q & 7) << 4)));
            #pragma unroll
            for (int f = 0; f < 4; f++) {
                int s = f * 16 + q;
                short8 vf = *(const short8*)(const void*)(Vb[bi] + s * 128 + (kb ^ ((s & 7) << 4)));
                oacc[f] = __builtin_amdgcn_mfma_f32_16x16x32_bf16(pa, vf, oacc[f], 0, 0, 0);
            }
        }
    }
    float inv = 1.0f / l_run;
    #pragma unroll
    for (int r = 0; r < 4; r++) {
        float ir = __shfl(inv, (lane & 48) | (g * 4 + r));
        int row_g = b * T_SEQ + qt * 64 + wave * 16 + g * 4 + r;
        #pragma unroll
        for (int f = 0; f < 4; f++) {
            size_t xi = (size_t)row_g * DMODEL + hh * HSZ + f * 16 + q;
            x[xi] += oacc[f][r] * ir;
        }
    }
}

// ---------------------------------------------------------------------------
// Loss pass 1: per-row online logsumexp over logits (float4) -> nll[row]
// ---------------------------------------------------------------------------
__global__ __launch_bounds__(256) void loss1_kernel(
    const float* __restrict__ logits, const int* __restrict__ targets,
    float* __restrict__ nll)
{
    int r = blockIdx.x, tid = threadIdx.x;
    const float* row = logits + (size_t)r * VOCAB;
    const float4* row4 = (const float4*)row;
    float m = -3.4e38f, s = 0.f;
    for (int v = tid; v < VOCAB / 4; v += 256) {
        float4 x4 = row4[v];
        float lm = fmaxf(fmaxf(x4.x, x4.y), fmaxf(x4.z, x4.w));
        float nm = fmaxf(m, lm);
        s = s * __expf(m - nm) + __expf(x4.x - nm) + __expf(x4.y - nm)
          + __expf(x4.z - nm) + __expf(x4.w - nm);
        m = nm;
    }
    if (tid == 0) {
        float xv = row[VOCAB - 1];
        float nm = fmaxf(m, xv);
        s = s * __expf(m - nm) + __expf(xv - nm);
        m = nm;
    }
    __shared__ float ms[256], ssh[256];
    ms[tid] = m; ssh[tid] = s;
    __syncthreads();
    for (int o = 128; o > 0; o >>= 1) {
        if (tid < o) {
            float m1 = ms[tid], s1 = ssh[tid];
            float m2 = ms[tid + o], s2 = ssh[tid + o];
            float nm = fmaxf(m1, m2);
            ssh[tid] = s1 * __expf(m1 - nm) + s2 * __expf(m2 - nm);
            ms[tid] = nm;
        }
        __syncthreads();
    }
    if (tid == 0) nll[r] = logf(ssh[0]) + ms[0] - row[targets[r]];
}

__global__ __launch_bounds__(256) void loss2_kernel(
    const float* __restrict__ nll, float* __restrict__ out)
{
    int tid = threadIdx.x;
    float s = 0.f;
    for (int i = tid; i < MROWS; i += 256) s += nll[i];
    __shared__ float red[256];
    red[tid] = s;
    __syncthreads();
    for (int o = 128; o > 0; o >>= 1) {
        if (tid < o) red[tid] += red[tid + o];
        __syncthreads();
    }
    if (tid == 0) out[0] = red[0] * (1.0f / MROWS);
}

// ---------------------------------------------------------------------------
extern "C" void kernel_launch(void* const* d_in, const int* in_sizes, int n_in,
                              void* d_out, int out_size, void* d_ws, size_t ws_size,
                              hipStream_t stream)
{
    const int*   idx  = (const int*)d_in[0];
    const int*   tgt  = (const int*)d_in[1];
    const float* tok  = (const float*)d_in[2];
    const float* pos  = (const float*)d_in[3];
    const float* Wq   = (const float*)d_in[4];
    const float* Wk   = (const float*)d_in[5];
    const float* Wv   = (const float*)d_in[6];
    const float* ln1g = (const float*)d_in[7];
    const float* ln1b = (const float*)d_in[8];
    const float* ln2g = (const float*)d_in[9];
    const float* ln2b = (const float*)d_in[10];
    const float* fc1w = (const float*)d_in[11];
    const float* fc1b = (const float*)d_in[12];
    const float* fc2w = (const float*)d_in[13];
    const float* fc2b = (const float*)d_in[14];
    const float* lnfg = (const float*)d_in[15];
    const float* lnfb = (const float*)d_in[16];
    const float* lmw  = (const float*)d_in[17];
    const float* lmb  = (const float*)d_in[18];

    char* ws = (char*)d_ws;
    float*          x    = (float*)(ws + 0);                  // 8.39 MB
    unsigned short* h    = (unsigned short*)(ws + 8388608);   // 4.19 MB
    unsigned short* qkv  = (unsigned short*)(ws + 12582912);  // 12.58 MB
    unsigned short* vt   = (unsigned short*)(ws + 25165824);  // 4.19 MB
    unsigned short* mid  = (unsigned short*)(ws + 29360128);  // 16.78 MB
    float*          nll  = (float*)(ws + 46137344);           // 8 KB
    float*          fc2p = (float*)(ws + 46145536);           // 16.78 MB [2][2048][1024]
    unsigned short* lmwt = (unsigned short*)(ws + 62922752);  // 103.02 MB [50304][1024]
    // end lmwt: 165945344
    const size_t UP_NEED = 442769408ull;
    bool upfront = (ws_size >= UP_NEED);
    unsigned short* qkvt = (unsigned short*)(ws + 165945344);
    unsigned short* fc1t, * fc2t;
    long qkvt_l, fc1t_l, fc2t_l;
    if (upfront) {
        fc1t = (unsigned short*)(ws + 241442816);
        fc2t = (unsigned short*)(ws + 342106112);
        qkvt_l = 3072 * 1024; fc1t_l = (long)FF * 1024; fc2t_l = (long)1024 * FF;
    } else {
        fc1t = (unsigned short*)(ws + 172236800);
        fc2t = (unsigned short*)(ws + 180625408);
        qkvt_l = 0; fc1t_l = 0; fc2t_l = 0;
    }
    float* logits = (float*)d_out;
    float* lossp  = logits + (size_t)MROWS * VOCAB;

    const long WQKV_L = (long)NHEAD * DMODEL * HSZ;
    if (upfront) {
        qkvpack_kernel<<<dim3(32, 2, 48 * NLAYER), 256, 0, stream>>>(
            Wq, Wk, Wv, qkvt, WQKV_L, qkvt_l);
        wtranspose_kernel<<<dim3(128, 32, NLAYER), 256, 0, stream>>>(
            fc1w, fc1t, DMODEL, FF, FF, (long)DMODEL * FF, fc1t_l);
        wtranspose_kernel<<<dim3(32, 128, NLAYER), 256, 0, stream>>>(
            fc2w, fc2t, FF, DMODEL, DMODEL, (long)FF * DMODEL, fc2t_l);
    }
    wtranspose_kernel<<<dim3(1572, 32, 1), 256, 0, stream>>>(
        lmw, lmwt, DMODEL, VOCAB, NPAD, 0, 0);

    // embed + layer-0 ln1 fused
    embed_ln_kernel<<<MROWS, 256, 0, stream>>>(idx, tok, pos, ln1g, ln1b, x, h);

    for (int l = 0; l < NLAYER; l++) {
        unsigned short* qkvt_p = qkvt + (size_t)l * qkvt_l;
        unsigned short* fc1t_p = fc1t + (size_t)l * fc1t_l;
        unsigned short* fc2t_p = fc2t + (size_t)l * fc2t_l;
        if (!upfront) {
            qkvpack_kernel<<<dim3(32, 2, 48), 256, 0, stream>>>(
                Wq + (size_t)l * WQKV_L, Wk + (size_t)l * WQKV_L,
                Wv + (size_t)l * WQKV_L, qkvt, WQKV_L, 0);
            wtranspose_kernel<<<dim3(128, 32, 1), 256, 0, stream>>>(
                fc1w + (size_t)l * DMODEL * FF, fc1t, DMODEL, FF, FF, 0, 0);
            wtranspose_kernel<<<dim3(32, 128, 1), 256, 0, stream>>>(
                fc2w + (size_t)l * FF * DMODEL, fc2t, FF, DMODEL, DMODEL, 0, 0);
        }
        gemm_qkv<<<dim3(16, 24), 256, 0, stream>>>(h, qkvt_p, qkv, vt);
        attn_fused_kernel<<<dim3(4, NHEAD, 8), 256, 0, stream>>>(qkv, vt, x);
        ln_kernel<<<MROWS, 256, 0, stream>>>(x, ln2g + l * DMODEL, ln2b + l * DMODEL, h);
        gemm_fc1<<<dim3(16, 32), 256, 0, stream>>>(h, fc1t_p, fc1b + (size_t)l * FF, mid);
        gemm_fc2<<<dim3(32, 8, 2), 256, 0, stream>>>(mid, fc2t_p, fc2p);
        const float* ng = (l < NLAYER - 1) ? ln1g + (l + 1) * DMODEL : lnfg;
        const float* nb = (l < NLAYER - 1) ? ln1b + (l + 1) * DMODEL : lnfb;
        fc2_merge_ln_kernel<<<MROWS, 256, 0, stream>>>(
            fc2p, fc2b + (size_t)l * DMODEL, ng, nb, x, h);
    }

    gemm_lm<<<dim3(8, 393), 512, 0, stream>>>(h, lmwt, lmb, logits);

    loss1_kernel<<<MROWS, 256, 0, stream>>>(logits, tgt, nll);
    loss2_kernel<<<1, 256, 0, stream>>>(nll, lossp);
}

// Round 10
// 2119.953 us; speedup vs baseline: 1.0647x; 1.0012x over previous
//
#include <hip/hip_runtime.h>

#define T_SEQ 256
#define DMODEL 1024
#define NHEAD 16
#define HSZ 64
#define NLAYER 12
#define VOCAB 50257
#define NPAD 50304
#define FF 4096
#define MROWS 2048

using short8 = __attribute__((ext_vector_type(8))) short;
using f32x4  = __attribute__((ext_vector_type(4))) float;

__device__ __forceinline__ float bf2f(unsigned short u) {
    unsigned int x = ((unsigned int)u) << 16;
    return __builtin_bit_cast(float, x);
}
__device__ __forceinline__ unsigned short f2bf(float f) {
    unsigned int u = __builtin_bit_cast(unsigned int, f);
    unsigned int r = (u + 0x7fffu + ((u >> 16) & 1u)) >> 16;
    return (unsigned short)r;
}
__device__ __forceinline__ void async_copy16(const void* g, void* l) {
    __builtin_amdgcn_global_load_lds(
        (const __attribute__((address_space(1))) unsigned int*)g,
        (__attribute__((address_space(3))) unsigned int*)l, 16, 0, 0);
}

// ---------------------------------------------------------------------------
// Shared LN tail
// ---------------------------------------------------------------------------
__device__ __forceinline__ void ln_tail(
    float4 v, const float* __restrict__ g, const float* __restrict__ b,
    int row, int tid, unsigned short* __restrict__ out)
{
    float s  = v.x + v.y + v.z + v.w;
    float ss = v.x * v.x + v.y * v.y + v.z * v.z + v.w * v.w;
    for (int o = 32; o > 0; o >>= 1) {
        s  += __shfl_down(s, o);
        ss += __shfl_down(ss, o);
    }
    __shared__ float ps[4], pss[4];
    int wave = tid >> 6, lane = tid & 63;
    if (lane == 0) { ps[wave] = s; pss[wave] = ss; }
    __syncthreads();
    float st  = ps[0] + ps[1] + ps[2] + ps[3];
    float sst = pss[0] + pss[1] + pss[2] + pss[3];
    float mu  = st * (1.0f / DMODEL);
    float var = sst * (1.0f / DMODEL) - mu * mu;
    float rstd = rsqrtf(var + 1e-5f);
    float4 gv = ((const float4*)g)[tid];
    float4 bv = ((const float4*)b)[tid];
    ushort4 o4;
    o4.x = f2bf((v.x - mu) * rstd * gv.x + bv.x);
    o4.y = f2bf((v.y - mu) * rstd * gv.y + bv.y);
    o4.z = f2bf((v.z - mu) * rstd * gv.z + bv.z);
    o4.w = f2bf((v.w - mu) * rstd * gv.w + bv.w);
    ((ushort4*)out)[(size_t)row * (DMODEL / 4) + tid] = o4;
}

// ---------------------------------------------------------------------------
// Embedding fused with layer-0 ln1
// ---------------------------------------------------------------------------
__global__ __launch_bounds__(256) void embed_ln_kernel(
    const int* __restrict__ idx, const float* __restrict__ tok,
    const float* __restrict__ pos, const float* __restrict__ g,
    const float* __restrict__ b, float* __restrict__ x,
    unsigned short* __restrict__ h)
{
    int row = blockIdx.x, tid = threadIdx.x;
    int t = row & (T_SEQ - 1);
    int token = idx[row];
    float4 a = ((const float4*)(tok + (size_t)token * DMODEL))[tid];
    float4 p = ((const float4*)(pos + (size_t)t * DMODEL))[tid];
    float4 v;
    v.x = a.x + p.x; v.y = a.y + p.y; v.z = a.z + p.z; v.w = a.w + p.w;
    ((float4*)(x + (size_t)row * DMODEL))[tid] = v;
    ln_tail(v, g, b, row, tid, h);
}

// ---------------------------------------------------------------------------
// Plain LayerNorm (ln2)
// ---------------------------------------------------------------------------
__global__ __launch_bounds__(256) void ln_kernel(
    const float* __restrict__ x, const float* __restrict__ g,
    const float* __restrict__ b, unsigned short* __restrict__ out)
{
    int row = blockIdx.x, tid = threadIdx.x;
    float4 v = ((const float4*)(x + (size_t)row * DMODEL))[tid];
    ln_tail(v, g, b, row, tid, out);
}

// ---------------------------------------------------------------------------
// fc2 partial merge + residual + NEXT layer's ln1 (or lnf), fused
// ---------------------------------------------------------------------------
__global__ __launch_bounds__(256) void fc2_merge_ln_kernel(
    const float* __restrict__ part, const float* __restrict__ bias,
    const float* __restrict__ g, const float* __restrict__ b,
    float* __restrict__ x, unsigned short* __restrict__ h)
{
    int row = blockIdx.x, tid = threadIdx.x;
    size_t o = (size_t)row * (DMODEL / 4) + tid;
    float4 p0 = ((const float4*)part)[o];
    float4 p1 = ((const float4*)part)[o + MROWS * (DMODEL / 4)];
    float4 bv = ((const float4*)bias)[tid];
    float4 v = ((float4*)x)[o];
    v.x += p0.x + p1.x + bv.x;
    v.y += p0.y + p1.y + bv.y;
    v.z += p0.z + p1.z + bv.z;
    v.w += p0.w + p1.w + bv.w;
    ((float4*)x)[o] = v;
    ln_tail(v, g, b, row, tid, h);
}

// ---------------------------------------------------------------------------
// Weight transpose: in [R,C] f32 -> out [C,R] bf16; ushort2-vectorized writes
// ---------------------------------------------------------------------------
__global__ __launch_bounds__(256) void wtranspose_kernel(
    const float* __restrict__ in, unsigned short* __restrict__ out,
    int R, int C, int Cout, long in_l, long out_l)
{
    int lyr = blockIdx.z;
    in  += (size_t)lyr * in_l;
    out += (size_t)lyr * out_l;
    __shared__ float tile[32][33];
    int tx = threadIdx.x & 31, ty = threadIdx.x >> 5;
    int c0 = blockIdx.x * 32, r0 = blockIdx.y * 32;
    #pragma unroll
    for (int i = 0; i < 4; i++) {
        int r = r0 + ty + i * 8, c = c0 + tx;
        tile[ty + i * 8][tx] = (c < C) ? in[(size_t)r * C + c] : 0.f;
    }
    __syncthreads();
    int wrl = (threadIdx.x & 15) * 2;   // local r (even), this thread: r, r+1
    int wcl = threadIdx.x >> 4;         // local c base (16 per pass)
    #pragma unroll
    for (int i = 0; i < 2; i++) {
        int c = c0 + wcl + i * 16, r = r0 + wrl;
        if (c < Cout) {
            ushort2 w;
            w.x = f2bf(tile[wrl][wcl + i * 16]);
            w.y = f2bf(tile[wrl + 1][wcl + i * 16]);
            *(ushort2*)(out + (size_t)c * R + r) = w;
        }
    }
}

// ---------------------------------------------------------------------------
// QKV weight pack: Wq/Wk/Wv [H,D,HS] f32 -> out[n, d] bf16, n=seg*1024+h*64+s
// ushort2-vectorized writes
// ---------------------------------------------------------------------------
__global__ __launch_bounds__(256) void qkvpack_kernel(
    const float* __restrict__ Wq, const float* __restrict__ Wk,
    const float* __restrict__ Wv, unsigned short* __restrict__ out,
    long w_l, long out_l)
{
    int z = blockIdx.z;
    int lyr = z / 48, r48 = z % 48;
    int seg = r48 >> 4, hh = r48 & 15;
    const float* W = (seg == 0 ? Wq : seg == 1 ? Wk : Wv)
                     + (size_t)lyr * w_l + (size_t)hh * DMODEL * HSZ;
    unsigned short* o = out + (size_t)lyr * out_l
                      + (size_t)(seg * 1024 + hh * 64) * DMODEL;
    __shared__ float tile[32][33];
    int tx = threadIdx.x & 31, ty = threadIdx.x >> 5;
    int d0 = blockIdx.x * 32, s0 = blockIdx.y * 32;
    #pragma unroll
    for (int i = 0; i < 4; i++)
        tile[ty + i * 8][tx] = W[(size_t)(d0 + ty + i * 8) * HSZ + s0 + tx];
    __syncthreads();
    int wdl = (threadIdx.x & 15) * 2;   // local d (even)
    int wsl = threadIdx.x >> 4;         // local s base
    #pragma unroll
    for (int i = 0; i < 2; i++) {
        int s = s0 + wsl + i * 16, d = d0 + wdl;
        ushort2 w;
        w.x = f2bf(tile[wdl][wsl + i * 16]);
        w.y = f2bf(tile[wdl + 1][wsl + i * 16]);
        *(ushort2*)(o + (size_t)s * DMODEL + d) = w;
    }
}

// ---------------------------------------------------------------------------
// Shared bf16 MFMA GEMM core (single-buffer 2-barrier).
// BM = (WAVES/2)*MF*16, per-wave tile = MF*16 x 64.
// ---------------------------------------------------------------------------
template<int MF, int WAVES, bool QKV, bool RELU, bool RES, bool CBF16>
__device__ __forceinline__ void gemm_core(
    const unsigned short* __restrict__ A, int lda,
    const unsigned short* __restrict__ Bt, int ldb,
    const float* __restrict__ bias,
    void* __restrict__ Cv, int ldc,
    const float* __restrict__ res, int ldr,
    int N, int K,
    unsigned short* __restrict__ vtout)
{
    constexpr int BM = (WAVES / 2) * MF * 16;
    constexpr int BJ = 16 / WAVES;
    __shared__ __align__(16) char As[BM * 128];
    __shared__ __align__(16) char Bs[128 * 128];
    int tid = threadIdx.x;
    int wave = tid >> 6, lane = tid & 63;
    int wr = wave >> 1, wc = wave & 1;
    int m0 = blockIdx.x * BM, n0 = blockIdx.y * 128;

    f32x4 acc[MF][4];
    #pragma unroll
    for (int m = 0; m < MF; m++)
        #pragma unroll
        for (int n = 0; n < 4; n++)
            acc[m][n] = (f32x4){0.f, 0.f, 0.f, 0.f};

    int ksw = (((lane & 7) ^ (lane >> 3)) << 4);
    int KT = K >> 6;
    for (int kt = 0; kt < KT; kt++) {
        int k0 = kt << 6;
        __syncthreads();
        #pragma unroll
        for (int j = 0; j < MF; j++) {
            int row = (wave * MF + j) * 8 + (lane >> 3);
            const char* src = (const char*)A + ((size_t)(m0 + row) * lda + k0) * 2 + ksw;
            async_copy16(src, As + (wave * MF + j) * 1024);
        }
        #pragma unroll
        for (int j = 0; j < BJ; j++) {
            int nrow = (wave * BJ + j) * 8 + (lane >> 3);
            const char* src = (const char*)Bt + ((size_t)(n0 + nrow) * ldb + k0) * 2 + ksw;
            async_copy16(src, Bs + (wave * BJ + j) * 1024);
        }
        __syncthreads();
        #pragma unroll
        for (int ks = 0; ks < 2; ks++) {
            int kb = ks * 64 + ((lane >> 4) << 4);
            short8 a[MF], b[4];
            #pragma unroll
            for (int m = 0; m < MF; m++) {
                int r = wr * (MF * 16) + m * 16 + (lane & 15);
                a[m] = *(const short8*)(const void*)(As + r * 128 + (kb ^ ((r & 7) << 4)));
            }
            #pragma unroll
            for (int n = 0; n < 4; n++) {
                int c = wc * 64 + n * 16 + (lane & 15);
                b[n] = *(const short8*)(const void*)(Bs + c * 128 + (kb ^ ((c & 7) << 4)));
            }
            #pragma unroll
            for (int m = 0; m < MF; m++)
                #pragma unroll
                for (int n = 0; n < 4; n++)
                    acc[m][n] = __builtin_amdgcn_mfma_f32_16x16x32_bf16(a[m], b[n], acc[m][n], 0, 0, 0);
        }
    }
    #pragma unroll
    for (int m = 0; m < MF; m++) {
        int rowb = m0 + wr * (MF * 16) + m * 16 + ((lane >> 4) << 2);
        #pragma unroll
        for (int n = 0; n < 4; n++) {
            int col = n0 + wc * 64 + n * 16 + (lane & 15);
            if (col < N) {
                float bi = bias ? bias[col] : 0.f;
                #pragma unroll
                for (int r2 = 0; r2 < 4; r2++) {
                    float v = acc[m][n][r2] + bi;
                    if (RELU) v = fmaxf(v, 0.f);
                    int row = rowb + r2;
                    if (RES) v += res[(size_t)row * ldr + col];
                    if (QKV && col >= 2048) {
                        int hh = (col - 2048) >> 6, sdim = (col - 2048) & 63;
                        int bb = row >> 8, tt = row & 255;
                        vtout[((((size_t)bb * NHEAD + hh) * HSZ + sdim) * T_SEQ) + tt] = f2bf(v);
                    } else if (CBF16) {
                        ((unsigned short*)Cv)[(size_t)row * ldc + col] = f2bf(v);
                    } else {
                        ((float*)Cv)[(size_t)row * ldc + col] = v;
                    }
                }
            }
        }
    }
}

__global__ __launch_bounds__(256) void gemm_qkv(
    const unsigned short* __restrict__ A, const unsigned short* __restrict__ Bt,
    unsigned short* __restrict__ C, unsigned short* __restrict__ vtout)
{
    gemm_core<4, 4, true, false, false, true>(
        A, DMODEL, Bt, DMODEL, nullptr, C, 3072, nullptr, 0, 3072, DMODEL, vtout);
}

__global__ __launch_bounds__(256) void gemm_fc1(
    const unsigned short* __restrict__ A, const unsigned short* __restrict__ Bt,
    const float* __restrict__ bias, unsigned short* __restrict__ C)
{
    gemm_core<4, 4, false, true, false, true>(
        A, DMODEL, Bt, DMODEL, bias, C, FF, nullptr, 0, FF, DMODEL, nullptr);
}

// fc2 split-K: blockIdx.z selects K-half (2048 each); writes f32 partials.
__global__ __launch_bounds__(256) void gemm_fc2(
    const unsigned short* __restrict__ A, const unsigned short* __restrict__ Bt,
    float* __restrict__ part)
{
    int z = blockIdx.z;
    gemm_core<2, 4, false, false, false, false>(
        A + z * 2048, FF, Bt + z * 2048, FF, nullptr,
        part + (size_t)z * MROWS * DMODEL, DMODEL, nullptr, 0,
        DMODEL, 2048, nullptr);
}

// LM head: 8 waves, 256x128 tile (R9: 293us, 30% MfmaUtil, VGPR 64).
__global__ __launch_bounds__(512) void gemm_lm(
    const unsigned short* __restrict__ A, const unsigned short* __restrict__ Bt,
    const float* __restrict__ bias, float* __restrict__ C)
{
    gemm_core<4, 8, false, false, false, false>(
        A, DMODEL, Bt, DMODEL, bias, C, VOCAB, nullptr, 0, VOCAB, DMODEL, nullptr);
}

// ---------------------------------------------------------------------------
// Fused flash attention (MFMA), ALL-RESIDENT K/V: qt<=3 so all tiles fit LDS
// (72 KB -> 2 blocks/CU). One barrier total; k-loop runs barrier-free with
// waves fully independent.
// ---------------------------------------------------------------------------
__global__ __launch_bounds__(256) void attn_fused_kernel(
    const unsigned short* __restrict__ qkv, const unsigned short* __restrict__ vt,
    float* __restrict__ x)
{
    int qt = blockIdx.x, hh = blockIdx.y, b = blockIdx.z;
    int tid = threadIdx.x;
    int wave = tid >> 6, lane = tid & 63;
    int g = lane >> 4, q = lane & 15;

    __shared__ __align__(16) char Kb[4][8192];
    __shared__ __align__(16) char Vb[4][8192];
    __shared__ __align__(16) char Plds[4][2048];

    int qrow = b * T_SEQ + qt * 64 + wave * 16 + q;
    const char* qp = (const char*)qkv + ((size_t)qrow * 3072 + hh * HSZ) * 2;
    short8 qreg[2];
    qreg[0] = *(const short8*)(const void*)(qp + (g << 4));
    qreg[1] = *(const short8*)(const void*)(qp + 64 + (g << 4));

    char* Pw = Plds[wave];

    f32x4 oacc[4];
    #pragma unroll
    for (int f = 0; f < 4; f++) oacc[f] = (f32x4){0.f, 0.f, 0.f, 0.f};
    float m_run = -1e30f, l_run = 0.f;

    int srow = wave * 8 + (lane >> 3);
    int sbyte = ((lane & 7) << 4) ^ ((srow & 7) << 4);

    // stage ALL k-tiles 0..qt, then one barrier
    for (int kt = 0; kt <= qt; kt++) {
        #pragma unroll
        for (int c = 0; c < 2; c++) {
            int row = c * 32 + srow;
            const char* src = (const char*)qkv +
                ((size_t)(b * T_SEQ + kt * 64 + row) * 3072 + 1024 + hh * HSZ) * 2 + sbyte;
            async_copy16(src, Kb[kt] + c * 4096 + wave * 1024);
        }
        #pragma unroll
        for (int c = 0; c < 2; c++) {
            int row = c * 32 + srow;
            const char* src = (const char*)vt +
                (((size_t)(b * NHEAD + hh) * HSZ + row) * T_SEQ + kt * 64) * 2 + sbyte;
            async_copy16(src, Vb[kt] + c * 4096 + wave * 1024);
        }
    }
    __syncthreads();   // vmcnt(0) drain: all tiles resident; no more barriers

    for (int kt = 0; kt <= qt; kt++) {
        f32x4 sacc[4];
        #pragma unroll
        for (int f = 0; f < 4; f++) sacc[f] = (f32x4){0.f, 0.f, 0.f, 0.f};
        #pragma unroll
        for (int ks = 0; ks < 2; ks++) {
            int kb = ks * 64 + (g << 4);
            #pragma unroll
            for (int f = 0; f < 4; f++) {
                int u = f * 16 + q;
                short8 kf = *(const short8*)(const void*)(Kb[kt] + u * 128 + (kb ^ ((u & 7) << 4)));
                sacc[f] = __builtin_amdgcn_mfma_f32_16x16x32_bf16(kf, qreg[ks], sacc[f], 0, 0, 0);
            }
        }
        float sv[4][4];
        #pragma unroll
        for (int f = 0; f < 4; f++)
            #pragma unroll
            for (int r = 0; r < 4; r++) {
                float v = sacc[f][r] * 0.125f;
                if (kt == qt) {
                    int u_loc = f * 16 + g * 4 + r;
                    if (u_loc > wave * 16 + q) v = -1e30f;
                }
                sv[f][r] = v;
            }
        float pm = -1e30f;
        #pragma unroll
        for (int f = 0; f < 4; f++)
            #pragma unroll
            for (int r = 0; r < 4; r++) pm = fmaxf(pm, sv[f][r]);
        pm = fmaxf(pm, __shfl_xor(pm, 16));
        pm = fmaxf(pm, __shfl_xor(pm, 32));
        float mnew = fmaxf(m_run, pm);
        float corr = __expf(m_run - mnew);
        float p[4][4];
        float ls = 0.f;
        #pragma unroll
        for (int f = 0; f < 4; f++)
            #pragma unroll
            for (int r = 0; r < 4; r++) {
                p[f][r] = __expf(sv[f][r] - mnew);
                ls += p[f][r];
            }
        ls += __shfl_xor(ls, 16);
        ls += __shfl_xor(ls, 32);
        l_run = l_run * corr + ls;
        m_run = mnew;
        #pragma unroll
        for (int r = 0; r < 4; r++) {
            float cr = __shfl(corr, (lane & 48) | (g * 4 + r));
            #pragma unroll
            for (int f = 0; f < 4; f++) oacc[f][r] *= cr;
        }
        #pragma unroll
        for (int f = 0; f < 4; f++)
            #pragma unroll
            for (int rp = 0; rp < 2; rp++) {
                int ue = f * 16 + g * 4 + rp * 2;
                unsigned int pk = (unsigned int)f2bf(p[f][rp * 2])
                                | ((unsigned int)f2bf(p[f][rp * 2 + 1]) << 16);
                *(unsigned int*)(void*)(Pw + q * 128 + ((ue * 2) ^ ((q & 7) << 4))) = pk;
            }
        #pragma unroll
        for (int ks = 0; ks < 2; ks++) {
            int kb = ks * 64 + (g << 4);
            short8 pa = *(const short8*)(const void*)(Pw + q * 128 + (kb ^ ((q & 7) << 4)));
            #pragma unroll
            for (int f = 0; f < 4; f++) {
                int s = f * 16 + q;
                short8 vf = *(const short8*)(const void*)(Vb[kt] + s * 128 + (kb ^ ((s & 7) << 4)));
                oacc[f] = __builtin_amdgcn_mfma_f32_16x16x32_bf16(pa, vf, oacc[f], 0, 0, 0);
            }
        }
    }
    float inv = 1.0f / l_run;
    #pragma unroll
    for (int r = 0; r < 4; r++) {
        float ir = __shfl(inv, (lane & 48) | (g * 4 + r));
        int row_g = b * T_SEQ + qt * 64 + wave * 16 + g * 4 + r;
        #pragma unroll
        for (int f = 0; f < 4; f++) {
            size_t xi = (size_t)row_g * DMODEL + hh * HSZ + f * 16 + q;
            x[xi] += oacc[f][r] * ir;
        }
    }
}

// ---------------------------------------------------------------------------
// Loss pass 1: per-row online logsumexp over logits (float4) -> nll[row]
// ---------------------------------------------------------------------------
__global__ __launch_bounds__(256) void loss1_kernel(
    const float* __restrict__ logits, const int* __restrict__ targets,
    float* __restrict__ nll)
{
    int r = blockIdx.x, tid = threadIdx.x;
    const float* row = logits + (size_t)r * VOCAB;
    const float4* row4 = (const float4*)row;
    float m = -3.4e38f, s = 0.f;
    for (int v = tid; v < VOCAB / 4; v += 256) {
        float4 x4 = row4[v];
        float lm = fmaxf(fmaxf(x4.x, x4.y), fmaxf(x4.z, x4.w));
        float nm = fmaxf(m, lm);
        s = s * __expf(m - nm) + __expf(x4.x - nm) + __expf(x4.y - nm)
          + __expf(x4.z - nm) + __expf(x4.w - nm);
        m = nm;
    }
    if (tid == 0) {
        float xv = row[VOCAB - 1];
        float nm = fmaxf(m, xv);
        s = s * __expf(m - nm) + __expf(xv - nm);
        m = nm;
    }
    __shared__ float ms[256], ssh[256];
    ms[tid] = m; ssh[tid] = s;
    __syncthreads();
    for (int o = 128; o > 0; o >>= 1) {
        if (tid < o) {
            float m1 = ms[tid], s1 = ssh[tid];
            float m2 = ms[tid + o], s2 = ssh[tid + o];
            float nm = fmaxf(m1, m2);
            ssh[tid] = s1 * __expf(m1 - nm) + s2 * __expf(m2 - nm);
            ms[tid] = nm;
        }
        __syncthreads();
    }
    if (tid == 0) nll[r] = logf(ssh[0]) + ms[0] - row[targets[r]];
}

__global__ __launch_bounds__(256) void loss2_kernel(
    const float* __restrict__ nll, float* __restrict__ out)
{
    int tid = threadIdx.x;
    float s = 0.f;
    for (int i = tid; i < MROWS; i += 256) s += nll[i];
    __shared__ float red[256];
    red[tid] = s;
    __syncthreads();
    for (int o = 128; o > 0; o >>= 1) {
        if (tid < o) red[tid] += red[tid + o];
        __syncthreads();
    }
    if (tid == 0) out[0] = red[0] * (1.0f / MROWS);
}

// ---------------------------------------------------------------------------
extern "C" void kernel_launch(void* const* d_in, const int* in_sizes, int n_in,
                              void* d_out, int out_size, void* d_ws, size_t ws_size,
                              hipStream_t stream)
{
    const int*   idx  = (const int*)d_in[0];
    const int*   tgt  = (const int*)d_in[1];
    const float* tok  = (const float*)d_in[2];
    const float* pos  = (const float*)d_in[3];
    const float* Wq   = (const float*)d_in[4];
    const float* Wk   = (const float*)d_in[5];
    const float* Wv   = (const float*)d_in[6];
    const float* ln1g = (const float*)d_in[7];
    const float* ln1b = (const float*)d_in[8];
    const float* ln2g = (const float*)d_in[9];
    const float* ln2b = (const float*)d_in[10];
    const float* fc1w = (const float*)d_in[11];
    const float* fc1b = (const float*)d_in[12];
    const float* fc2w = (const float*)d_in[13];
    const float* fc2b = (const float*)d_in[14];
    const float* lnfg = (const float*)d_in[15];
    const float* lnfb = (const float*)d_in[16];
    const float* lmw  = (const float*)d_in[17];
    const float* lmb  = (const float*)d_in[18];

    char* ws = (char*)d_ws;
    float*          x    = (float*)(ws + 0);                  // 8.39 MB
    unsigned short* h    = (unsigned short*)(ws + 8388608);   // 4.19 MB
    unsigned short* qkv  = (unsigned short*)(ws + 12582912);  // 12.58 MB
    unsigned short* vt   = (unsigned short*)(ws + 25165824);  // 4.19 MB
    unsigned short* mid  = (unsigned short*)(ws + 29360128);  // 16.78 MB
    float*          nll  = (float*)(ws + 46137344);           // 8 KB
    float*          fc2p = (float*)(ws + 46145536);           // 16.78 MB [2][2048][1024]
    unsigned short* lmwt = (unsigned short*)(ws + 62922752);  // 103.02 MB [50304][1024]
    const size_t UP_NEED = 442769408ull;
    bool upfront = (ws_size >= UP_NEED);
    unsigned short* qkvt = (unsigned short*)(ws + 165945344);
    unsigned short* fc1t, * fc2t;
    long qkvt_l, fc1t_l, fc2t_l;
    if (upfront) {
        fc1t = (unsigned short*)(ws + 241442816);
        fc2t = (unsigned short*)(ws + 342106112);
        qkvt_l = 3072 * 1024; fc1t_l = (long)FF * 1024; fc2t_l = (long)1024 * FF;
    } else {
        fc1t = (unsigned short*)(ws + 172236800);
        fc2t = (unsigned short*)(ws + 180625408);
        qkvt_l = 0; fc1t_l = 0; fc2t_l = 0;
    }
    float* logits = (float*)d_out;
    float* lossp  = logits + (size_t)MROWS * VOCAB;

    const long WQKV_L = (long)NHEAD * DMODEL * HSZ;
    if (upfront) {
        qkvpack_kernel<<<dim3(32, 2, 48 * NLAYER), 256, 0, stream>>>(
            Wq, Wk, Wv, qkvt, WQKV_L, qkvt_l);
        wtranspose_kernel<<<dim3(128, 32, NLAYER), 256, 0, stream>>>(
            fc1w, fc1t, DMODEL, FF, FF, (long)DMODEL * FF, fc1t_l);
        wtranspose_kernel<<<dim3(32, 128, NLAYER), 256, 0, stream>>>(
            fc2w, fc2t, FF, DMODEL, DMODEL, (long)FF * DMODEL, fc2t_l);
    }
    wtranspose_kernel<<<dim3(1572, 32, 1), 256, 0, stream>>>(
        lmw, lmwt, DMODEL, VOCAB, NPAD, 0, 0);

    embed_ln_kernel<<<MROWS, 256, 0, stream>>>(idx, tok, pos, ln1g, ln1b, x, h);

    for (int l = 0; l < NLAYER; l++) {
        unsigned short* qkvt_p = qkvt + (size_t)l * qkvt_l;
        unsigned short* fc1t_p = fc1t + (size_t)l * fc1t_l;
        unsigned short* fc2t_p = fc2t + (size_t)l * fc2t_l;
        if (!upfront) {
            qkvpack_kernel<<<dim3(32, 2, 48), 256, 0, stream>>>(
                Wq + (size_t)l * WQKV_L, Wk + (size_t)l * WQKV_L,
                Wv + (size_t)l * WQKV_L, qkvt, WQKV_L, 0);
            wtranspose_kernel<<<dim3(128, 32, 1), 256, 0, stream>>>(
                fc1w + (size_t)l * DMODEL * FF, fc1t, DMODEL, FF, FF, 0, 0);
            wtranspose_kernel<<<dim3(32, 128, 1), 256, 0, stream>>>(
                fc2w + (size_t)l * FF * DMODEL, fc2t, FF, DMODEL, DMODEL, 0, 0);
        }
        gemm_qkv<<<dim3(16, 24), 256, 0, stream>>>(h, qkvt_p, qkv, vt);
        attn_fused_kernel<<<dim3(4, NHEAD, 8), 256, 0, stream>>>(qkv, vt, x);
        ln_kernel<<<MROWS, 256, 0, stream>>>(x, ln2g + l * DMODEL, ln2b + l * DMODEL, h);
        gemm_fc1<<<dim3(16, 32), 256, 0, stream>>>(h, fc1t_p, fc1b + (size_t)l * FF, mid);
        gemm_fc2<<<dim3(32, 8, 2), 256, 0, stream>>>(mid, fc2t_p, fc2p);
        const float* ng = (l < NLAYER - 1) ? ln1g + (l + 1) * DMODEL : lnfg;
        const float* nb = (l < NLAYER - 1) ? ln1b + (l + 1) * DMODEL : lnfb;
        fc2_merge_ln_kernel<<<MROWS, 256, 0, stream>>>(
            fc2p, fc2b + (size_t)l * DMODEL, ng, nb, x, h);
    }

    gemm_lm<<<dim3(8, 393), 512, 0, stream>>>(h, lmwt, lmb, logits);

    loss1_kernel<<<MROWS, 256, 0, stream>>>(logits, tgt, nll);
    loss2_kernel<<<1, 256, 0, stream>>>(nll, lossp);
}